// Round 4
// baseline (597.968 us; speedup 1.0000x reference)
//
#include <hip/hip_runtime.h>

// IBRNet aggregator, fused fp32. R4 = R3 minus the VGPR clamp:
// __launch_bounds__(256,4) forced 64 VGPRs -> ~112 floats/thread spilled to
// scratch (WRITE_SIZE 8->235 MB). Unclamped, the ~110-reg live set fits and
// spill traffic disappears.
//
// Layout (all fp32):
//  features   (2,8,32,32^3)   idx ((b*8+n)*32+c)*32768+v
//  mask/depth (2,8,1,32^3)    idx (b*8+n)*32768+v
//  voxel_dir  (2,8,3,32^3)    idx ((b*8+n)*3+d)*32768+v
//  weights row-major [o][i];  out (2,32,32^3) idx (b*32+c)*32768+v
//
// Wave = 8 views x 8 voxels: n = lane&7, vsub = lane>>3.
// Cross-view sum = shfl_xor {1,2,4} (within 32-lane halves -> DPP-cheap).
// MLP o-loops rolled (unroll 2): weight rows via wave-uniform scalar loads;
// dynamic-indexed layer outputs round-trip a 32-row per-tid LDS column
// (same-thread write/read: no barrier needed).
// Single-pass weighted var: var = E[x^2] - mu^2*(2 - s), s = sum(w)
// (exact algebra for the reference's  sum w (x - mu)^2  with mu = sum w x).

#define G3 32768

__device__ __forceinline__ float eluf(float x) {
    return x > 0.0f ? x : __expf(x) - 1.0f;
}
__device__ __forceinline__ float sigmoidf(float x) {
    return 1.0f / (1.0f + __expf(-x));
}
__device__ __forceinline__ float red8(float v) {
    v += __shfl_xor(v, 1, 64);
    v += __shfl_xor(v, 2, 64);
    v += __shfl_xor(v, 4, 64);
    return v;
}

template <int K>
__device__ __forceinline__ float dotrow(const float* __restrict__ row,
                                        const float (&x)[K]) {
    float a0 = 0.f, a1 = 0.f, a2 = 0.f, a3 = 0.f;
#pragma unroll
    for (int c = 0; c < K; c += 4) {
        a0 += row[c + 0] * x[c + 0];
        a1 += row[c + 1] * x[c + 1];
        a2 += row[c + 2] * x[c + 2];
        a3 += row[c + 3] * x[c + 3];
    }
    return (a0 + a1) + (a2 + a3);
}

__global__ __launch_bounds__(256) void ibr_kernel(
    const float* __restrict__ features, const float* __restrict__ mask,
    const float* __restrict__ vdepth, const float* __restrict__ vdir,
    const float* __restrict__ rde_w1, const float* __restrict__ rde_b1,
    const float* __restrict__ rde_w2, const float* __restrict__ rde_b2,
    const float* __restrict__ base_w1, const float* __restrict__ base_b1,
    const float* __restrict__ base_w2, const float* __restrict__ base_b2,
    const float* __restrict__ vis_w1, const float* __restrict__ vis_b1,
    const float* __restrict__ vis_w2, const float* __restrict__ vis_b2,
    const float* __restrict__ vis2_w1, const float* __restrict__ vis2_b1,
    const float* __restrict__ vis2_w2, const float* __restrict__ vis2_b2,
    const float* __restrict__ stat_w, const float* __restrict__ stat_b,
    float* __restrict__ out) {
    __shared__ float scratch[32 * 256];  // [row][tid], 32 KB per 4-wave block

    const int tid = threadIdx.x;
    const int lane = tid & 63;
    const int n = lane & 7;      // view (low bits -> cheap shuffles)
    const int vsub = lane >> 3;  // voxel-within-wave
    const int w = blockIdx.x * 4 + (tid >> 6);  // wave id 0..8191
    const int b = w >> 12;
    const int v = ((w & 4095) << 3) + vsub;  // block covers 32 consec voxels
    const int bn = b * 8 + n;

    // ---- input loads issued early (overlap with rde compute) --------------
    const float m = mask[bn * G3 + v];
    const float r0 = vdir[(bn * 3 + 0) * G3 + v];
    const float r1 = vdir[(bn * 3 + 1) * G3 + v];
    const float r2 = vdir[(bn * 3 + 2) * G3 + v];
    const float r3 = vdepth[bn * G3 + v];
    float fin[32];
#pragma unroll
    for (int c = 0; c < 32; ++c) fin[c] = features[(bn * 32 + c) * G3 + v];

    // ---- rde MLP: 4 -> 16 -> 32, feats = features + rde -------------------
    float h16[16];
#pragma unroll
    for (int o = 0; o < 16; ++o) {
        float a = rde_b1[o] + rde_w1[o * 4 + 0] * r0 + rde_w1[o * 4 + 1] * r1 +
                  rde_w1[o * 4 + 2] * r2 + rde_w1[o * 4 + 3] * r3;
        h16[o] = eluf(a);
    }
    float f[32];
#pragma unroll
    for (int o = 0; o < 32; ++o) {
        float a = rde_b2[o];
#pragma unroll
        for (int c = 0; c < 16; ++c) a += rde_w2[o * 16 + c] * h16[c];
        f[o] = eluf(a) + fin[o];
    }

    // ---- mask-weighted mean/var (single pass) -----------------------------
    const float msum = red8(m);
    const float invA = 1.0f / (msum + 1e-8f);
    const float wt = m * invA;
    const float sA = msum * invA;  // sum of weights (~1)

    float mean[32], var[32];
#pragma unroll
    for (int c = 0; c < 32; ++c) {
        const float p = wt * f[c];
        mean[c] = red8(p);
        var[c] = red8(p * f[c]);  // E[x^2] for now
    }
#pragma unroll
    for (int c = 0; c < 32; ++c)
        var[c] = var[c] - mean[c] * mean[c] * (2.0f - sA);

    // ---- base MLP: 96 -> 64 -> 32 -----------------------------------------
    float h0[32], h1[32];
#pragma unroll 2
    for (int o = 0; o < 32; ++o) {
        const float* row = base_w1 + o * 96;
        float a = dotrow<32>(row, mean) + dotrow<32>(row + 32, var) +
                  dotrow<32>(row + 64, f) + base_b1[o];
        scratch[o * 256 + tid] = eluf(a);
    }
#pragma unroll
    for (int c = 0; c < 32; ++c) h0[c] = scratch[c * 256 + tid];
#pragma unroll 2
    for (int o = 0; o < 32; ++o) {
        const float* row = base_w1 + (o + 32) * 96;
        float a = dotrow<32>(row, mean) + dotrow<32>(row + 32, var) +
                  dotrow<32>(row + 64, f) + base_b1[o + 32];
        scratch[o * 256 + tid] = eluf(a);
    }
#pragma unroll
    for (int c = 0; c < 32; ++c) h1[c] = scratch[c * 256 + tid];

    float x[32];
#pragma unroll 2
    for (int o = 0; o < 32; ++o) {
        const float* row = base_w2 + o * 64;
        scratch[o * 256 + tid] =
            eluf(dotrow<32>(row, h0) + dotrow<32>(row + 32, h1) + base_b2[o]);
    }
#pragma unroll
    for (int c = 0; c < 32; ++c) x[c] = scratch[c * 256 + tid];

    // ---- vis MLP: (x*wt) 32 -> 32 -> 33 -----------------------------------
    float xin[32];
#pragma unroll
    for (int c = 0; c < 32; ++c) xin[c] = x[c] * wt;
    float hv[32];
#pragma unroll 2
    for (int o = 0; o < 32; ++o) {
        scratch[o * 256 + tid] =
            eluf(dotrow<32>(vis_w1 + o * 32, xin) + vis_b1[o]);
    }
#pragma unroll
    for (int c = 0; c < 32; ++c) hv[c] = scratch[c * 256 + tid];
#pragma unroll 2
    for (int o = 0; o < 32; ++o) {
        scratch[o * 256 + tid] =
            eluf(dotrow<32>(vis_w2 + o * 32, hv) + vis_b2[o]);
    }
    const float visn =
        sigmoidf(eluf(dotrow<32>(vis_w2 + 32 * 32, hv) + vis_b2[32])) * m;
#pragma unroll
    for (int c = 0; c < 32; ++c) x[c] += scratch[c * 256 + tid];

    // ---- vis2 MLP: (x*visn) 32 -> 32 -> 1 ---------------------------------
#pragma unroll
    for (int c = 0; c < 32; ++c) xin[c] = x[c] * visn;
#pragma unroll 2
    for (int o = 0; o < 32; ++o) {
        scratch[o * 256 + tid] =
            eluf(dotrow<32>(vis2_w1 + o * 32, xin) + vis2_b1[o]);
    }
#pragma unroll
    for (int c = 0; c < 32; ++c) hv[c] = scratch[c * 256 + tid];
    const float visv = sigmoidf(dotrow<32>(vis2_w2, hv) + vis2_b2[0]) * m;

    // ---- vis-weighted mean/var (single pass) + stat layer -----------------
    const float b0 = red8(visv);
    const float invC = 1.0f / (b0 + 1e-8f);
    const float wt2 = visv * invC;
    const float sC = b0 * invC;
    const float wm = sC * 0.125f;  // mean over views of weight

    float mean2[32], var2[32];
#pragma unroll
    for (int c = 0; c < 32; ++c) {
        const float p = wt2 * x[c];
        mean2[c] = red8(p);
        var2[c] = red8(p * x[c]);
    }
#pragma unroll
    for (int c = 0; c < 32; ++c)
        var2[c] = var2[c] - mean2[c] * mean2[c] * (2.0f - sC);

    // stat layer is per-voxel: each lane computes its 4 rows (o = 4n..4n+3)
    const int obase = n * 4;
#pragma unroll
    for (int j = 0; j < 4; ++j) {
        const float* row = stat_w + (obase + j) * 65;
        float a = dotrow<32>(row, mean2) + dotrow<32>(row + 32, var2) +
                  row[64] * wm + stat_b[obase + j];
        out[(b * 32 + obase + j) * G3 + v] = eluf(a);
    }
}

extern "C" void kernel_launch(void* const* d_in, const int* in_sizes, int n_in,
                              void* d_out, int out_size, void* d_ws,
                              size_t ws_size, hipStream_t stream) {
    const float* features = (const float*)d_in[0];
    const float* mask = (const float*)d_in[1];
    const float* vdepth = (const float*)d_in[2];
    const float* vdir = (const float*)d_in[3];
    const float* rde_w1 = (const float*)d_in[4];
    const float* rde_b1 = (const float*)d_in[5];
    const float* rde_w2 = (const float*)d_in[6];
    const float* rde_b2 = (const float*)d_in[7];
    const float* base_w1 = (const float*)d_in[8];
    const float* base_b1 = (const float*)d_in[9];
    const float* base_w2 = (const float*)d_in[10];
    const float* base_b2 = (const float*)d_in[11];
    const float* vis_w1 = (const float*)d_in[12];
    const float* vis_b1 = (const float*)d_in[13];
    const float* vis_w2 = (const float*)d_in[14];
    const float* vis_b2 = (const float*)d_in[15];
    const float* vis2_w1 = (const float*)d_in[16];
    const float* vis2_b1 = (const float*)d_in[17];
    const float* vis2_w2 = (const float*)d_in[18];
    const float* vis2_b2 = (const float*)d_in[19];
    const float* stat_w = (const float*)d_in[20];
    const float* stat_b = (const float*)d_in[21];

    // 8192 waves total; 256-thread blocks (4 waves) -> 2048 blocks
    ibr_kernel<<<2048, 256, 0, stream>>>(
        features, mask, vdepth, vdir, rde_w1, rde_b1, rde_w2, rde_b2, base_w1,
        base_b1, base_w2, base_b2, vis_w1, vis_b1, vis_w2, vis_b2, vis2_w1,
        vis2_b1, vis2_w2, vis2_b2, stat_w, stat_b, (float*)d_out);
}

// Round 5
// 243.438 us; speedup vs baseline: 2.4563x; 2.4563x over previous
//
#include <hip/hip_runtime.h>

// IBRNet aggregator R5: MFMA (f16 in, fp32 acc) for all 32-wide GEMM layers.
//
// Column space: (b, v, n) -> 524288 columns. Block = 128 cols = 16 voxels x
// 8 views, col = vi*8 + n. 4 waves/block; each wave owns N-tiles {w, w+4}.
// Activations live in LDS  Y[col][k]  (f16, Kpad=104) -- the MFMA B-operand
// layout: lane holds B[k][n]: n=lane&15, k=(lane>>4)*8+j  -> ds_read_b128.
// Weights pre-converted fp32->f16 into d_ws (prep kernel): A-operand
// A[m][k]: m=lane&15, k=(lane>>4)*8+j -> global_load_dwordx4, L1-hot.
// C/D: col=lane&15, row=(lane>>4)*4+reg.
//
// Y slot timeline (k ranges):
//   A: mean->[0:32) var->[32:64) f->[64:96)
//   base1 reads [0:96) -> h -> [0:64)
//   base2 reads [0:64) -> x -> [64:96), x*wt -> [0:32)
//   vis1 reads [0:32)  -> hv -> [32:64)
//   vis2 reads [32:64) -> x_res -> [0:32), visn (row 32) -> LDS f32
//   x-update: x+=x_res -> [64:96), x*visn -> [0:32)
//   vis2_1 reads [0:32) -> hv2 -> [32:64)
//   vis2_2 (VALU) reads [32:64) -> visv
//   mean2/var2 (VALU) read [64:96) -> write col vi*8 [0:64); stat (VALU).
// Reductions over views = sums over 8 consecutive cols (VALU, fp32).

#define G3 32768
#define KP 104

typedef _Float16 h8 __attribute__((ext_vector_type(8)));
typedef _Float16 h4 __attribute__((ext_vector_type(4)));
typedef float f4 __attribute__((ext_vector_type(4)));

__device__ __forceinline__ float eluf(float x) {
    return x > 0.0f ? x : __expf(x) - 1.0f;
}
__device__ __forceinline__ float sigmoidf(float x) {
    return 1.0f / (1.0f + __expf(-x));
}

// d_ws layout (element offsets in _Float16)
#define WS_BW1 0      // base_w1 [64][96]
#define WS_BW2 6144   // base_w2 [32][64]
#define WS_VW1 8192   // vis_w1  [32][32]
#define WS_VW2 9216   // vis_w2  [48][32]  rows 33..47 zeroed
#define WS_V2W1 10752 // vis2_w1 [32][32]
#define WS_H_TOT 11776
#define WS_VB2_BYTE (WS_H_TOT * 2)  // fp32 vis_b2 padded [48]

__global__ void prep_kernel(const float* __restrict__ bw1,
                            const float* __restrict__ bw2,
                            const float* __restrict__ vw1,
                            const float* __restrict__ vw2,
                            const float* __restrict__ v2w1,
                            const float* __restrict__ vb2,
                            _Float16* __restrict__ wh,
                            float* __restrict__ vb2p) {
    int t = blockIdx.x * blockDim.x + threadIdx.x;
    int stride = gridDim.x * blockDim.x;
    for (int i = t; i < 6144; i += stride) wh[WS_BW1 + i] = (_Float16)bw1[i];
    for (int i = t; i < 2048; i += stride) wh[WS_BW2 + i] = (_Float16)bw2[i];
    for (int i = t; i < 1024; i += stride) wh[WS_VW1 + i] = (_Float16)vw1[i];
    for (int i = t; i < 1536; i += stride)
        wh[WS_VW2 + i] = (i < 1056) ? (_Float16)vw2[i] : (_Float16)0.0f;
    for (int i = t; i < 1024; i += stride) wh[WS_V2W1 + i] = (_Float16)v2w1[i];
    for (int i = t; i < 48; i += stride) vb2p[i] = (i < 33) ? vb2[i] : 0.0f;
}

// Accumulate C-tiles for one layer: wave's 2 N-tiles x MT M-tiles.
template <int K, int KS, int MT>
__device__ __forceinline__ void mfma_tiles(const _Float16* __restrict__ Wf,
                                           const _Float16* __restrict__ Y,
                                           int srck0, int wave, int lane,
                                           f4 acc[2][4]) {
    const int q = lane >> 4, nlo = lane & 15;
#pragma unroll
    for (int j = 0; j < 2; ++j) {
        const int col = (wave + j * 4) * 16 + nlo;
        const _Float16* yc = Y + col * KP + srck0 + q * 8;
        h8 bf[KS];
#pragma unroll
        for (int kt = 0; kt < KS; ++kt) bf[kt] = *(const h8*)(yc + kt * 32);
#pragma unroll
        for (int mt = 0; mt < MT; ++mt) {
            f4 a = {0.f, 0.f, 0.f, 0.f};
            const _Float16* wr = Wf + (mt * 16 + nlo) * K + q * 8;
#pragma unroll
            for (int kt = 0; kt < KS; ++kt)
                a = __builtin_amdgcn_mfma_f32_16x16x32_f16(
                    *(const h8*)(wr + kt * 32), bf[kt], a, 0, 0, 0);
            acc[j][mt] = a;
        }
    }
}

// Standard epilogue: +bias, elu, f16 store to Y[col][dstk0 + m].
template <int MT>
__device__ __forceinline__ void epi_store(f4 acc[2][4],
                                          const float* __restrict__ bias,
                                          _Float16* __restrict__ Y, int dstk0,
                                          int wave, int lane) {
    const int q = lane >> 4, nlo = lane & 15;
#pragma unroll
    for (int j = 0; j < 2; ++j) {
        const int col = (wave + j * 4) * 16 + nlo;
#pragma unroll
        for (int mt = 0; mt < MT; ++mt) {
            f4 bb = *(const f4*)(bias + mt * 16 + q * 4);
            f4 v = acc[j][mt];
            h4 hv;
#pragma unroll
            for (int r = 0; r < 4; ++r) hv[r] = (_Float16)eluf(v[r] + bb[r]);
            *(h4*)(Y + col * KP + dstk0 + mt * 16 + q * 4) = hv;
        }
    }
}

__global__ __launch_bounds__(256) void ibr_mfma(
    const float* __restrict__ features, const float* __restrict__ mask,
    const float* __restrict__ vdepth, const float* __restrict__ vdir,
    const float* __restrict__ rde_w1, const float* __restrict__ rde_b1,
    const float* __restrict__ rde_w2, const float* __restrict__ rde_b2,
    const float* __restrict__ base_b1, const float* __restrict__ base_b2,
    const float* __restrict__ vis_b1, const float* __restrict__ vis2_b1,
    const float* __restrict__ vis2_w2, const float* __restrict__ vis2_b2,
    const float* __restrict__ stat_w, const float* __restrict__ stat_b,
    const _Float16* __restrict__ wh, const float* __restrict__ vb2p,
    float* __restrict__ out) {
    __shared__ _Float16 Y[128 * KP];  // 26624 B
    __shared__ float wtc[128], mval[128], visn_s[128], visv_s[128], wt2c[128];
    __shared__ float sA_v[16], wm_v[16];

    const int tid = threadIdx.x;
    const int lane = tid & 63;
    const int wave = tid >> 6;
    const int bb = blockIdx.x;
    const int b = bb >> 11;            // 2048 blocks per batch
    const int v0 = (bb & 2047) << 4;   // 16 voxels per block

    // ---- A1: features -> Y[col][64+c] (f16); mask -> mval ------------------
    {
        const int n = tid >> 5, c = tid & 31;
        const float* fp = features + (((b * 8 + n) * 32 + c) << 15) + v0;
        f4 x0 = *(const f4*)(fp);
        f4 x1 = *(const f4*)(fp + 4);
        f4 x2 = *(const f4*)(fp + 8);
        f4 x3 = *(const f4*)(fp + 12);
        float va[16] = {x0[0], x0[1], x0[2], x0[3], x1[0], x1[1], x1[2], x1[3],
                        x2[0], x2[1], x2[2], x2[3], x3[0], x3[1], x3[2], x3[3]};
#pragma unroll
        for (int vi = 0; vi < 16; ++vi)
            Y[(vi * 8 + n) * KP + 64 + c] = (_Float16)va[vi];
    }
    if (tid < 128)
        mval[tid] = mask[((b * 8 + (tid & 7)) << 15) + v0 + (tid >> 3)];
    __syncthreads();

    // ---- rde MLP (fp32 VALU) + add into Y; wt, sA --------------------------
    if (tid < 128) {
        const int n = tid & 7, vi = tid >> 3, col = tid;
        const int bn = b * 8 + n, v = v0 + vi;
        const float r0 = vdir[(bn * 3 + 0) * G3 + v];
        const float r1 = vdir[(bn * 3 + 1) * G3 + v];
        const float r2 = vdir[(bn * 3 + 2) * G3 + v];
        const float r3 = vdepth[bn * G3 + v];
        float h16[16];
#pragma unroll
        for (int o = 0; o < 16; ++o) {
            float a = rde_b1[o] + rde_w1[o * 4 + 0] * r0 +
                      rde_w1[o * 4 + 1] * r1 + rde_w1[o * 4 + 2] * r2 +
                      rde_w1[o * 4 + 3] * r3;
            h16[o] = eluf(a);
        }
        float msum = 0.f;
#pragma unroll
        for (int k = 0; k < 8; ++k) msum += mval[vi * 8 + k];
        const float inv = 1.0f / (msum + 1e-8f);
        wtc[col] = mval[col] * inv;
        if (n == 0) sA_v[vi] = msum * inv;

        _Float16* yc = Y + col * KP + 64;
#pragma unroll
        for (int og = 0; og < 4; ++og) {
            h8 cur = *(h8*)(yc + og * 8);
#pragma unroll
            for (int oo = 0; oo < 8; ++oo) {
                const int o = og * 8 + oo;
                float a = rde_b2[o];
#pragma unroll
                for (int c = 0; c < 16; ++c) a += rde_w2[o * 16 + c] * h16[c];
                cur[oo] = (_Float16)((float)cur[oo] + eluf(a));
            }
            *(h8*)(yc + og * 8) = cur;
        }
    }
    __syncthreads();

    // ---- mask-weighted mean/var -> Y[0:32),[32:64) (broadcast to 8 cols) ---
#pragma unroll
    for (int t2 = 0; t2 < 2; ++t2) {
        const int idx = tid * 2 + t2;     // 0..511
        const int vi = idx >> 5, c = idx & 31;
        float s = 0.f, s2 = 0.f;
#pragma unroll
        for (int n = 0; n < 8; ++n) {
            const int col = vi * 8 + n;
            const float xv = (float)Y[col * KP + 64 + c];
            const float p = wtc[col] * xv;
            s += p;
            s2 += p * xv;
        }
        const float var = s2 - s * s * (2.0f - sA_v[vi]);
        const _Float16 hm = (_Float16)s, hva = (_Float16)var;
#pragma unroll
        for (int n = 0; n < 8; ++n) {
            Y[(vi * 8 + n) * KP + c] = hm;
            Y[(vi * 8 + n) * KP + 32 + c] = hva;
        }
    }
    __syncthreads();

    // ---- base1: 96 -> 64 ---------------------------------------------------
    {
        f4 acc[2][4];
        mfma_tiles<96, 3, 4>(wh + WS_BW1, Y, 0, wave, lane, acc);
        __syncthreads();
        epi_store<4>(acc, base_b1, Y, 0, wave, lane);
    }
    __syncthreads();

    // ---- base2: 64 -> 32; write x -> [64:96) and x*wt -> [0:32) ------------
    {
        f4 acc[2][4];
        mfma_tiles<64, 2, 2>(wh + WS_BW2, Y, 0, wave, lane, acc);
        __syncthreads();
        const int q = lane >> 4, nlo = lane & 15;
#pragma unroll
        for (int j = 0; j < 2; ++j) {
            const int col = (wave + j * 4) * 16 + nlo;
            const float wt = wtc[col];
#pragma unroll
            for (int mt = 0; mt < 2; ++mt) {
                f4 bbv = *(const f4*)(base_b2 + mt * 16 + q * 4);
                f4 v = acc[j][mt];
                h4 hx, hxw;
#pragma unroll
                for (int r = 0; r < 4; ++r) {
                    const float xv = eluf(v[r] + bbv[r]);
                    hx[r] = (_Float16)xv;
                    hxw[r] = (_Float16)(xv * wt);
                }
                *(h4*)(Y + col * KP + 64 + mt * 16 + q * 4) = hx;
                *(h4*)(Y + col * KP + mt * 16 + q * 4) = hxw;
            }
        }
    }
    __syncthreads();

    // ---- vis1: 32 -> 32 ----------------------------------------------------
    {
        f4 acc[2][4];
        mfma_tiles<32, 1, 2>(wh + WS_VW1, Y, 0, wave, lane, acc);
        __syncthreads();
        epi_store<2>(acc, vis_b1, Y, 32, wave, lane);
    }
    __syncthreads();

    // ---- vis2: 32 -> 33 (padded to 48 rows); x_res -> [0:32), visn ---------
    {
        f4 acc[2][4];
        mfma_tiles<32, 1, 3>(wh + WS_VW2, Y, 32, wave, lane, acc);
        __syncthreads();
        const int q = lane >> 4, nlo = lane & 15;
#pragma unroll
        for (int j = 0; j < 2; ++j) {
            const int col = (wave + j * 4) * 16 + nlo;
#pragma unroll
            for (int mt = 0; mt < 2; ++mt) {
                f4 bbv = *(const f4*)(vb2p + mt * 16 + q * 4);
                f4 v = acc[j][mt];
                h4 hv;
#pragma unroll
                for (int r = 0; r < 4; ++r)
                    hv[r] = (_Float16)eluf(v[r] + bbv[r]);
                *(h4*)(Y + col * KP + mt * 16 + q * 4) = hv;
            }
            if (q == 0) {  // row m = 32: the vis channel
                const float vv = acc[j][2][0] + vb2p[32];
                visn_s[col] = sigmoidf(eluf(vv)) * mval[col];
            }
        }
    }
    __syncthreads();

    // ---- x update: x += x_res; write x -> [64:96), x*visn -> [0:32) --------
#pragma unroll
    for (int i = 0; i < 16; ++i) {
        const int idx = tid * 16 + i;  // 0..4095
        const int col = idx >> 5, c = idx & 31;
        const float xr = (float)Y[col * KP + c];
        const float xo = (float)Y[col * KP + 64 + c];
        const float xn = xo + xr;
        Y[col * KP + 64 + c] = (_Float16)xn;
        Y[col * KP + c] = (_Float16)(xn * visn_s[col]);
    }
    __syncthreads();

    // ---- vis2_1: 32 -> 32 --------------------------------------------------
    {
        f4 acc[2][4];
        mfma_tiles<32, 1, 2>(wh + WS_V2W1, Y, 0, wave, lane, acc);
        __syncthreads();
        epi_store<2>(acc, vis2_b1, Y, 32, wave, lane);
    }
    __syncthreads();

    // ---- vis2_2 (1x32, VALU) -> visv ---------------------------------------
    if (tid < 128) {
        const int col = tid;
        const _Float16* yc = Y + col * KP + 32;
        float a0 = vis2_b2[0], a1 = 0.f, a2 = 0.f, a3 = 0.f;
#pragma unroll
        for (int c = 0; c < 32; c += 4) {
            a0 += vis2_w2[c + 0] * (float)yc[c + 0];
            a1 += vis2_w2[c + 1] * (float)yc[c + 1];
            a2 += vis2_w2[c + 2] * (float)yc[c + 2];
            a3 += vis2_w2[c + 3] * (float)yc[c + 3];
        }
        visv_s[col] = sigmoidf((a0 + a1) + (a2 + a3)) * mval[col];
    }
    __syncthreads();
    if (tid < 128) {
        const int vi = tid >> 3, n = tid & 7, col = tid;
        float b0 = 0.f;
#pragma unroll
        for (int k = 0; k < 8; ++k) b0 += visv_s[vi * 8 + k];
        const float inv = 1.0f / (b0 + 1e-8f);
        wt2c[col] = visv_s[col] * inv;
        if (n == 0) wm_v[vi] = b0 * inv * 0.125f;
    }
    __syncthreads();

    // ---- vis-weighted mean2/var2 -> col vi*8, k [0:32)/[32:64) -------------
#pragma unroll
    for (int t2 = 0; t2 < 2; ++t2) {
        const int idx = tid * 2 + t2;
        const int vi = idx >> 5, c = idx & 31;
        float s = 0.f, s2 = 0.f;
#pragma unroll
        for (int n = 0; n < 8; ++n) {
            const int col = vi * 8 + n;
            const float xv = (float)Y[col * KP + 64 + c];
            const float p = wt2c[col] * xv;
            s += p;
            s2 += p * xv;
        }
        const float sC = wm_v[vi] * 8.0f;
        const float var = s2 - s * s * (2.0f - sC);
        Y[(vi * 8) * KP + c] = (_Float16)s;
        Y[(vi * 8) * KP + 32 + c] = (_Float16)var;
    }
    __syncthreads();

    // ---- stat layer (VALU): 16 voxels x 32 outs, 2 outs/thread -------------
    {
        const int vi = tid >> 4;
        const int o0 = (tid & 15) * 2;
        const _Float16* ym = Y + (vi * 8) * KP;
        const float wm = wm_v[vi];
#pragma unroll
        for (int jo = 0; jo < 2; ++jo) {
            const int o = o0 + jo;
            const float* row = stat_w + o * 65;
            float a0 = 0.f, a1 = 0.f, a2 = 0.f, a3 = 0.f;
#pragma unroll
            for (int c = 0; c < 32; c += 4) {
                a0 += row[c + 0] * (float)ym[c + 0];
                a1 += row[c + 1] * (float)ym[c + 1];
                a2 += row[c + 2] * (float)ym[c + 2];
                a3 += row[c + 3] * (float)ym[c + 3];
            }
#pragma unroll
            for (int c = 0; c < 32; c += 4) {
                a0 += row[32 + c + 0] * (float)ym[32 + c + 0];
                a1 += row[32 + c + 1] * (float)ym[32 + c + 1];
                a2 += row[32 + c + 2] * (float)ym[32 + c + 2];
                a3 += row[32 + c + 3] * (float)ym[32 + c + 3];
            }
            float a = (a0 + a1) + (a2 + a3) + row[64] * wm + stat_b[o];
            out[((b * 32 + o) << 15) + v0 + vi] = eluf(a);
        }
    }
}

extern "C" void kernel_launch(void* const* d_in, const int* in_sizes, int n_in,
                              void* d_out, int out_size, void* d_ws,
                              size_t ws_size, hipStream_t stream) {
    const float* features = (const float*)d_in[0];
    const float* mask = (const float*)d_in[1];
    const float* vdepth = (const float*)d_in[2];
    const float* vdir = (const float*)d_in[3];
    const float* rde_w1 = (const float*)d_in[4];
    const float* rde_b1 = (const float*)d_in[5];
    const float* rde_w2 = (const float*)d_in[6];
    const float* rde_b2 = (const float*)d_in[7];
    const float* base_w1 = (const float*)d_in[8];
    const float* base_b1 = (const float*)d_in[9];
    const float* base_w2 = (const float*)d_in[10];
    const float* base_b2 = (const float*)d_in[11];
    const float* vis_w1 = (const float*)d_in[12];
    const float* vis_b1 = (const float*)d_in[13];
    const float* vis_w2 = (const float*)d_in[14];
    const float* vis_b2 = (const float*)d_in[15];
    const float* vis2_w1 = (const float*)d_in[16];
    const float* vis2_b1 = (const float*)d_in[17];
    const float* vis2_w2 = (const float*)d_in[18];
    const float* vis2_b2 = (const float*)d_in[19];
    const float* stat_w = (const float*)d_in[20];
    const float* stat_b = (const float*)d_in[21];

    _Float16* wh = (_Float16*)d_ws;
    float* vb2p = (float*)((char*)d_ws + WS_VB2_BYTE);

    prep_kernel<<<24, 256, 0, stream>>>(base_w1, base_w2, vis_w1, vis_w2,
                                        vis2_w1, vis_b2, wh, vb2p);

    // 524288 cols / 128 per block = 4096 blocks
    ibr_mfma<<<4096, 256, 0, stream>>>(
        features, mask, vdepth, vdir, rde_w1, rde_b1, rde_w2, rde_b2, base_b1,
        base_b2, vis_b1, vis2_b1, vis2_w2, vis2_b2, stat_w, stat_b, wh, vb2p,
        (float*)d_out);
}